// Round 7
// baseline (128.271 us; speedup 1.0000x reference)
//
#include <hip/hip_runtime.h>
#include <math.h>

#define EDIM 128
#define NHEAD 16
#define HDIM 8
#define SEQ 2048
#define BATCH 4
#define NROW (BATCH*SEQ)            // 8192
// -scale*log2(e): folded into Q at projection time so sigmoid = rcp(1+exp2(dot))
#define QNEG (-0.35355339059327373f * 1.4426950408889634f)

#if __has_builtin(__builtin_amdgcn_exp2f)
#define EXP2F(x) __builtin_amdgcn_exp2f(x)
#else
#define EXP2F(x) exp2f(x)
#endif
#define RCPF(x) __builtin_amdgcn_rcpf(x)

typedef __attribute__((ext_vector_type(8))) short short8v;
typedef __attribute__((ext_vector_type(4))) short short4v;
typedef __attribute__((ext_vector_type(4))) float float4v;

union U16x8 { uint4 u; short8v s; };
union U16x4 { uint2 u; short4v s; };

#if __has_builtin(__builtin_amdgcn_mfma_f32_16x16x16bf16_1k)
#define MFMA_PV(a,b,c) __builtin_amdgcn_mfma_f32_16x16x16bf16_1k(a,b,c,0,0,0)
#else
static __device__ __forceinline__ float4v mfma_pv_asm(short4v a, short4v b, float4v c) {
  float4v d;
  asm("v_mfma_f32_16x16x16_bf16 %0, %1, %2, %3" : "=v"(d) : "v"(a), "v"(b), "v"(c));
  return d;
}
#define MFMA_PV(a,b,c) mfma_pv_asm(a,b,c)
#endif

// pack two floats to bf16x2, round-to-nearest-even-ish (values finite)
__device__ __forceinline__ unsigned pk_bf16(float a, float b) {
  unsigned ua = __float_as_uint(a), ub = __float_as_uint(b);
  unsigned lo = (ua + 0x7fffu + ((ua >> 16) & 1u)) >> 16;
  unsigned hi = (ub + 0x7fffu + ((ub >> 16) & 1u)) & 0xffff0000u;
  return lo | hi;
}

// ---------------------------------------------------------------------------
// One 16-row x 32-col projection tile for one weight matrix, given the shared
// A-frags. W is read fp32 DIRECTLY (8 contiguous floats of row n0+lq at
// k-offset) and cast in-register with pk_bf16 — bit-identical to the former
// cast4_kernel + bf16 reload path. B[k=qd*8+j][n=lq] = W[n][kk*32+qd*8+j].
//   D lane l: D[m=(l>>4)*4+r][n=l&15]
// MODE 0: Q scaled by QNEG -> bf16 [bh][s][8]
// MODE 1: K -> bf16 [bh][s][8]
// MODE 2: V -> bf16 tile-blocked transpose Vt[bh][t=s>>4][d][si=s&15]
// MODE 3: fp32 row-major [rows][128] (final output)
// ---------------------------------------------------------------------------
template<int MODE>
__device__ __forceinline__
void run_tile(const short8v a[4], const float* __restrict__ W,
              const float* __restrict__ bias, void* __restrict__ out,
              int row0, int lq, int qd, int n0)
{
  float4v D0 = {0.f, 0.f, 0.f, 0.f}, D1 = {0.f, 0.f, 0.f, 0.f};
  const float* wr = W + (size_t)(n0 + lq) * EDIM + qd * 8;
  #pragma unroll
  for (int kk = 0; kk < 4; ++kk) {
    const float4 f0 = *(const float4*)(wr + kk * 32);
    const float4 f1 = *(const float4*)(wr + kk * 32 + 4);
    const float4 g0 = *(const float4*)(wr + 16 * EDIM + kk * 32);
    const float4 g1 = *(const float4*)(wr + 16 * EDIM + kk * 32 + 4);
    U16x8 b0, b1;
    b0.u = make_uint4(pk_bf16(f0.x, f0.y), pk_bf16(f0.z, f0.w),
                      pk_bf16(f1.x, f1.y), pk_bf16(f1.z, f1.w));
    b1.u = make_uint4(pk_bf16(g0.x, g0.y), pk_bf16(g0.z, g0.w),
                      pk_bf16(g1.x, g1.y), pk_bf16(g1.z, g1.w));
    D0 = __builtin_amdgcn_mfma_f32_16x16x32_bf16(a[kk], b0.s, D0, 0, 0, 0);
    D1 = __builtin_amdgcn_mfma_f32_16x16x32_bf16(a[kk], b1.s, D1, 0, 0, 0);
  }

  const int nA = n0 + lq, nB = nA + 16;
  const float bzA = bias[nA], bzB = bias[nB];

  if (MODE == 3) {
    float* of = (float*)out + (size_t)(row0 + qd * 4) * EDIM + nA;
    #pragma unroll
    for (int r = 0; r < 4; ++r) {
      of[r * EDIM]      = D0[r] + bzA;
      of[r * EDIM + 16] = D1[r] + bzB;
    }
    return;
  }

  if (MODE == 2) {
    // Vt[bh][tg][d][si]: block = exactly one 16-s tile; si = qd*4 + r.
    const int b_ = row0 >> 11, srel = row0 & (SEQ - 1);
    const int tg = srel >> 4;
    unsigned short* oU = (unsigned short*)out;
    {
      const int bh = b_ * NHEAD + (nA >> 3), dv = nA & 7;
      uint2 p;
      p.x = pk_bf16(D0[0] + bzA, D0[1] + bzA);
      p.y = pk_bf16(D0[2] + bzA, D0[3] + bzA);
      *(uint2*)(oU + (size_t)bh * (SEQ * HDIM) + tg * 128 + dv * 16 + qd * 4) = p;
    }
    {
      const int bh = b_ * NHEAD + (nB >> 3), dv = nB & 7;
      uint2 p;
      p.x = pk_bf16(D1[0] + bzB, D1[1] + bzB);
      p.y = pk_bf16(D1[2] + bzB, D1[3] + bzB);
      *(uint2*)(oU + (size_t)bh * (SEQ * HDIM) + tg * 128 + dv * 16 + qd * 4) = p;
    }
    return;
  }

  // MODE 0/1: [bh][s][8] u16 elements; lane col fixed -> u16 scatter, rows r
  {
    const int b_ = row0 >> 11;
    const int srel = (row0 & (SEQ - 1)) + qd * 4;
    unsigned short* oU = (unsigned short*)out;
    const int bhA = b_ * NHEAD + (nA >> 3), dvA = nA & 7;
    const int bhB = bhA + 2;                      // nB = nA+16 -> h+2, same d
    unsigned short* pA = oU + ((size_t)bhA * SEQ + srel) * 8 + dvA;
    unsigned short* pB = oU + ((size_t)bhB * SEQ + srel) * 8 + dvA;
    #pragma unroll
    for (int r = 0; r < 4; ++r) {
      float vA = D0[r] + bzA, vB = D1[r] + bzB;
      if (MODE == 0) { vA *= QNEG; vB *= QNEG; }
      pA[r * 8] = (unsigned short)pk_bf16(vA, 0.f);
      pB[r * 8] = (unsigned short)pk_bf16(vB, 0.f);
    }
    return;
  }
}

// stage 16 rows of X as bf16 into XOR-swizzled LDS and load this wave's A-frags
//   A lane l: A[m=l&15][k=(l>>4)*8+j]
__device__ __forceinline__
void stage_and_afrags(const float* __restrict__ X, unsigned short* xs,
                      int row0, int tid, short8v a[4])
{
  {
    const int r = tid >> 4, c16 = tid & 15;
    const float4* src = (const float4*)(X + (size_t)(row0 + r) * EDIM + c16 * 8);
    const float4 f0 = src[0], f1 = src[1];
    uint4 v;
    v.x = pk_bf16(f0.x, f0.y); v.y = pk_bf16(f0.z, f0.w);
    v.z = pk_bf16(f1.x, f1.y); v.w = pk_bf16(f1.z, f1.w);
    const unsigned addr = (unsigned)(r * 256 + c16 * 16) ^ (unsigned)((r & 7) << 4);
    *(uint4*)((char*)xs + addr) = v;
  }
  __syncthreads();
  const int lane = tid & 63;
  const int lq = lane & 15, qd = lane >> 4;
  #pragma unroll
  for (int kk = 0; kk < 4; ++kk) {
    const unsigned addr =
        (unsigned)(lq * 256 + kk * 64 + qd * 16) ^ (unsigned)((lq & 7) << 4);
    a[kk] = *(const short8v*)((const char*)xs + addr);
  }
}

// ---------------------------------------------------------------------------
// Fused QKV: one block = 16 rows x all 3 projections. A-frags are shared
// across Q/K/V (loaded once), 24 MFMA per wave. Grid 512 blocks.
// ---------------------------------------------------------------------------
__global__ __launch_bounds__(256)
void qkv_fused_kernel(const float* __restrict__ X,
                      const float* __restrict__ Wq, const float* __restrict__ Wk,
                      const float* __restrict__ Wv,
                      const float* __restrict__ bq, const float* __restrict__ bk,
                      const float* __restrict__ bv,
                      unsigned* __restrict__ qb, unsigned* __restrict__ kb,
                      unsigned* __restrict__ vb)
{
  __shared__ unsigned short xs[16 * EDIM];        // 4 KB
  const int tid = threadIdx.x;
  const int row0 = blockIdx.x * 16;
  short8v a[4];
  stage_and_afrags(X, xs, row0, tid, a);
  const int lane = tid & 63, wv = tid >> 6;
  const int lq = lane & 15, qd = lane >> 4, n0 = wv * 32;
  run_tile<0>(a, Wq, bq, (void*)qb, row0, lq, qd, n0);
  run_tile<1>(a, Wk, bk, (void*)kb, row0, lq, qd, n0);
  run_tile<2>(a, Wv, bv, (void*)vb, row0, lq, qd, n0);
}

__global__ __launch_bounds__(256)
void oproj_kernel(const float* __restrict__ A, const float* __restrict__ Wo,
                  const float* __restrict__ bo, float* __restrict__ out)
{
  __shared__ unsigned short xs[16 * EDIM];        // 4 KB
  const int tid = threadIdx.x;
  const int row0 = blockIdx.x * 16;
  short8v a[4];
  stage_and_afrags(A, xs, row0, tid, a);
  const int lane = tid & 63, wv = tid >> 6;
  const int lq = lane & 15, qd = lane >> 4, n0 = wv * 32;
  run_tile<3>(a, Wo, bo, (void*)out, row0, lq, qd, n0);
}

// ---------------------------------------------------------------------------
// One 16q x 16k MFMA step.  (round-0 verified sigmoid path)
// S^T = mfma_16x16x32_bf16(A=K-rows, B=Q-frag) -> C[key][q]. Sigmoid
// elementwise; C-register reinterpreted as A-operand of mfma_16x16x16 gives
// the UN-transposed P, so out[q][d] = mfma(A=P, B=V-frag, acc). V-frag col 8
// is forced to 1.0 so acc col 8 accumulates the denominator.
// ---------------------------------------------------------------------------
template<bool DIAG>
__device__ __forceinline__
float4v attn_step(short8v kf, short8v qf, short4v vf, float4v acc,
                  int laneq, int quad)
{
  const float4v z = {0.f, 0.f, 0.f, 0.f};
  float4v st = __builtin_amdgcn_mfma_f32_16x16x32_bf16(kf, qf, z, 0, 0, 0);
  unsigned rb[4];
  #pragma unroll
  for (int r = 0; r < 4; ++r) {
    float s = RCPF(1.f + EXP2F(st[r]));           // Q carries -scale*log2e
    if (DIAG) s = (4 * quad + r <= laneq) ? s : 0.f;  // exact: sigma(-1e9)==0
    rb[r] = __float_as_uint(s) + 0x8000u;         // round-half-up to bf16
  }
  U16x4 p;
  p.u.x = __builtin_amdgcn_perm(rb[1], rb[0], 0x07060302u);
  p.u.y = __builtin_amdgcn_perm(rb[3], rb[2], 0x07060302u);
  return MFMA_PV(p.s, vf, acc);                   // A = P[q][k], B = V[k][d]
}

// V-frag loader from tile-blocked Vt[bh][t][d][si]: ONE dwordx2 from a
// contiguous 256B tile block. lanes laneq==8 -> bf16 1.0 (denominator col).
__device__ __forceinline__
short4v load_vfrag(const unsigned short* __restrict__ Vtbh, int t,
                   int quad, int d, bool is8)
{
  const unsigned short* p = Vtbh + t * 128 + d * 16 + 4 * quad;
  const uint2 v = *(const uint2*)p;
  U16x4 vf;
  vf.u.x = is8 ? 0x3F803F80u : v.x;
  vf.u.y = is8 ? 0x3F803F80u : v.y;
  return vf.s;
}

// epilogue: den = acc col 8; normalize and store rows of tile T
__device__ __forceinline__
void epilogue(float4v acc, int T, int bh, int laneq, int quad,
              float* __restrict__ out)
{
  const int b_ = bh >> 4, h = bh & 15;
  const int pidx = (quad * 16 + 8) << 2;          // lane holding col 8
  #pragma unroll
  for (int r = 0; r < 4; ++r) {
    const float den = __int_as_float(
        __builtin_amdgcn_ds_bpermute(pidx, __float_as_int(acc[r])));
    const float val = acc[r] * RCPF(den);         // den > 0
    const int row = 16 * T + 4 * quad + r;
    if (laneq < 8)
      out[(size_t)(b_ * SEQ + row) * EDIM + h * HDIM + laneq] = val;
  }
}

// ---------------------------------------------------------------------------
// Causal sigmoid-attention v11: v8 split-K x2 fold-pair schedule, with
// dwordx2 V-frag loads from tile-blocked Vt (contiguous 256B per tile).
// blockIdx low 6 bits = bh -> XCD = bh%8 (L2 locality).
// ---------------------------------------------------------------------------
__global__ __launch_bounds__(128, 8)
void attn_kernel(const unsigned* __restrict__ Qb, const unsigned* __restrict__ Kb,
                 const unsigned* __restrict__ Vb, float* __restrict__ out)
{
  __shared__ float cmb[2][64][4];                 // 2 KB

  const int bh    = blockIdx.x & 63;
  const int g     = blockIdx.x >> 6;              // 0..63
  const int w     = threadIdx.x >> 6;
  const int lane  = threadIdx.x & 63;
  const int laneq = lane & 15;
  const int quad  = lane >> 4;
  const int L = g, H = 127 - g;
  const int mL = (L + 1) >> 1, mH = (H + 1) >> 1;
  const int d   = laneq & 7;
  const bool is8 = (laneq == 8);

  const uint4* Kg = (const uint4*)Kb + (size_t)bh * 2048;
  const uint4* Qg = (const uint4*)Qb + (size_t)bh * 2048;
  const unsigned short* Vtbh = (const unsigned short*)Vb + (size_t)bh * SEQ * HDIM;

  // Q B-frags: lanes<16 hold the 8-dim row in quad 0 (k=0..7); zero others
  U16x8 qfl, qfh;
  {
    const uint4 rl = Qg[16 * L + laneq];
    const uint4 rh = Qg[16 * H + laneq];
    qfl.u = (lane < 16) ? rl : make_uint4(0u, 0u, 0u, 0u);
    qfh.u = (lane < 16) ? rh : make_uint4(0u, 0u, 0u, 0u);
  }

  float4v accL = {0.f, 0.f, 0.f, 0.f};
  float4v accH = {0.f, 0.f, 0.f, 0.f};

  if (w == 0) {
    // k-tiles [0,mL) dual (L+H), [mL,mH) H-only; no diags; prefetch 1 deep
    U16x8 kf; kf.u = Kg[laneq];
    short4v vf = load_vfrag(Vtbh, 0, quad, d, is8);
    #pragma unroll 2
    for (int t = 0; t < mH; ++t) {
      U16x8 kn; kn.u = Kg[16 * (t + 1) + laneq];  // t+1 <= mH <= 64: in-bounds
      short4v vn = load_vfrag(Vtbh, t + 1, quad, d, is8);
      if (t < mL) accL = attn_step<false>(kf.s, qfl.s, vf, accL, laneq, quad);
      accH = attn_step<false>(kf.s, qfh.s, vf, accH, laneq, quad);
      kf = kn; vf = vn;
    }
  } else {
    // L segment: [mL, L], diag at L
    U16x8 kf; kf.u = Kg[16 * mL + laneq];
    short4v vf = load_vfrag(Vtbh, mL, quad, d, is8);
    #pragma unroll 2
    for (int t = mL; t < L; ++t) {
      U16x8 kn; kn.u = Kg[16 * (t + 1) + laneq];
      short4v vn = load_vfrag(Vtbh, t + 1, quad, d, is8);
      accL = attn_step<false>(kf.s, qfl.s, vf, accL, laneq, quad);
      kf = kn; vf = vn;
    }
    accL = attn_step<true>(kf.s, qfl.s, vf, accL, laneq, quad);
    // H segment: [mH, H], diag at H
    kf.u = Kg[16 * mH + laneq];
    vf = load_vfrag(Vtbh, mH, quad, d, is8);
    #pragma unroll 2
    for (int t = mH; t < H; ++t) {
      U16x8 kn; kn.u = Kg[16 * (t + 1) + laneq];  // t+1 <= H = 127: in-bounds
      short4v vn = load_vfrag(Vtbh, t + 1, quad, d, is8);
      accH = attn_step<false>(kf.s, qfh.s, vf, accH, laneq, quad);
      kf = kn; vf = vn;
    }
    accH = attn_step<true>(kf.s, qfh.s, vf, accH, laneq, quad);

    *(float4*)&cmb[0][lane][0] = make_float4(accL[0], accL[1], accL[2], accL[3]);
    *(float4*)&cmb[1][lane][0] = make_float4(accH[0], accH[1], accH[2], accH[3]);
  }
  __syncthreads();

  if (w == 0) {
    const float4 pL = *(const float4*)&cmb[0][lane][0];
    const float4 pH = *(const float4*)&cmb[1][lane][0];
    accL[0] += pL.x; accL[1] += pL.y; accL[2] += pL.z; accL[3] += pL.w;
    accH[0] += pH.x; accH[1] += pH.y; accH[2] += pH.z; accH[3] += pH.w;
    epilogue(accL, L, bh, laneq, quad, out);
    epilogue(accH, H, bh, laneq, quad, out);
  }
}

// ---------------------------------------------------------------------------
extern "C" void kernel_launch(void* const* d_in, const int* in_sizes, int n_in,
                              void* d_out, int out_size, void* d_ws, size_t ws_size,
                              hipStream_t stream)
{
  const float* x  = (const float*)d_in[0];
  const float* Wq = (const float*)d_in[1];
  const float* bq = (const float*)d_in[2];
  const float* Wk = (const float*)d_in[3];
  const float* bk = (const float*)d_in[4];
  const float* Wv = (const float*)d_in[5];
  const float* bv = (const float*)d_in[6];
  const float* Wo = (const float*)d_in[7];
  const float* bo = (const float*)d_in[8];

  float* ws = (float*)d_ws;
  // layout: (64K floats reserved) | attn 1048576 f | Qb, Kb, Vt 524288 dw each
  float*    attn = ws + 65536;
  unsigned* Qb   = (unsigned*)(ws + 65536 + 1048576);
  unsigned* Kb   = Qb + (size_t)524288;
  unsigned* Vb   = Kb + (size_t)524288;

  qkv_fused_kernel<<<dim3(NROW / 16), 256, 0, stream>>>(x, Wq, Wk, Wv, bq, bk, bv,
                                                        Qb, Kb, Vb);
  attn_kernel<<<dim3(4096), 128, 0, stream>>>(Qb, Kb, Vb, attn);
  oproj_kernel<<<dim3(NROW / 16), 256, 0, stream>>>(attn, Wo, bo, (float*)d_out);
}